// Round 12
// baseline (192.907 us; speedup 1.0000x reference)
//
#include <hip/hip_runtime.h>
#include <math.h>

#define Hd 128
#define Rr 3
#define Ll 4
#define NPW 16   // nodes (M-rows) per wave
#define NW  4    // waves per block (256 threads)
#define SRP 136  // Sr row pitch in bf16 elems (272 B: 16-B aligned, 2-way-bank-benign)

typedef float f32x4 __attribute__((ext_vector_type(4)));
typedef short s16x8 __attribute__((ext_vector_type(8)));

__device__ __forceinline__ unsigned short f2bf(float f){
    unsigned u = __float_as_uint(f);
    return (unsigned short)((u + 0x7FFFu + ((u >> 16) & 1u)) >> 16);
}
__device__ __forceinline__ float bf2f(unsigned short h){
    return __uint_as_float(((unsigned)h) << 16);
}
// convert 8 consecutive f32 (global) -> bf16 A-fragment
__device__ __forceinline__ s16x8 cvt8(const float* p){
    float4 a = *(const float4*)p;
    float4 b = *(const float4*)(p + 4);
    float v[8] = {a.x, a.y, a.z, a.w, b.x, b.y, b.z, b.w};
    s16x8 r;
    #pragma unroll
    for (int j = 0; j < 8; ++j) r[j] = (short)f2bf(v[j]);
    return r;
}
__device__ __forceinline__ int lower_bound_i32(const int* __restrict__ a, int n, int key){
    int lo = 0, hi = n;
    while (lo < hi){
        int mid = (lo + hi) >> 1;
        if (a[mid] < key) lo = mid + 1; else hi = mid;
    }
    return lo;
}

// async global->LDS, 16B per lane; LDS dest = uniform base + lane*16
__device__ __forceinline__ void gload_lds16(const unsigned short* g, unsigned short* l){
    __builtin_amdgcn_global_load_lds(
        (const __attribute__((address_space(1))) void*)g,
        (__attribute__((address_space(3))) void*)l, 16, 0, 0);
}

// ---- McT = out_w @ wv (folded), bc = out_w @ bv + out_b  (verified r1-r11) ----
__global__ void fold_proj_kernel(const float* __restrict__ in_proj_w,
                                 const float* __restrict__ in_proj_b,
                                 const float* __restrict__ out_w,
                                 const float* __restrict__ out_b,
                                 float* __restrict__ McT,
                                 float* __restrict__ bc)
{
    const int i = blockIdx.x;   // k index
    const int j = threadIdx.x;  // n index
    float acc = 0.f;
    for (int k = 0; k < Hd; ++k)
        acc = fmaf(out_w[j * Hd + k], in_proj_w[(2 * Hd + k) * Hd + i], acc);
    McT[i * Hd + j] = acc;
    if (i == 0){
        float b = out_b[j];
        for (int k = 0; k < Hd; ++k)
            b = fmaf(out_w[j * Hd + k], in_proj_b[2 * Hd + k], b);
        bc[j] = b;
    }
}

// ---- quantize weights to bf16 MFMA B-fragments (verified r4-r11) ----
// frag elem j of lane l at (mat,kc,nc):  W[kc*32 + (l>>4)*8 + j][nc*16 + (l&15)]
__global__ void pack_kernel(const float* __restrict__ r_whh, const float* __restrict__ u_whh,
                            const float* __restrict__ r_wxh, const float* __restrict__ u_wxh,
                            const float* __restrict__ c_whh, const float* __restrict__ c_wxh,
                            const float* __restrict__ McT,
                            unsigned short* __restrict__ whi)
{
    const int mat  = blockIdx.y;   // 0..6
    const int tile = blockIdx.x;   // 0..31 : kc = tile>>3, nc = tile&7
    const int l    = threadIdx.x;  // 0..63
    const float* W;
    switch (mat){
        case 0: W = r_whh; break;  case 1: W = u_whh; break;
        case 2: W = r_wxh; break;  case 3: W = u_wxh; break;
        case 4: W = c_whh; break;  case 5: W = c_wxh; break;
        default: W = McT;
    }
    const int kc = tile >> 3, nc = tile & 7;
    const int kbase = kc * 32 + (l >> 4) * 8;
    const int n = nc * 16 + (l & 15);
    const size_t obase = ((size_t)(mat * 32 + tile) * 64 + l) * 8;
    #pragma unroll
    for (int j = 0; j < 8; ++j)
        whi[obase + j] = f2bf(W[(kbase + j) * Hd + n]);
}

// B-frag read from current half-buffer: kk = local kc (0/1), nc 0..7
#define BF_LDS(kk, nc) (*(const s16x8*)&WL[cur][(((kk) * 8 + (nc)) * 64 + l) * 8])

#define MM1(acc, AH, BH)                                                  \
    acc = __builtin_amdgcn_mfma_f32_16x16x32_bf16(AH, BH, acc, 0, 0, 0);

__global__ __launch_bounds__(256, 3) void gru_mfma_kernel(
    const float* __restrict__ x_rank,
    const int* __restrict__ valid_idx, int nv,
    const float* __restrict__ r_b, const float* __restrict__ u_b, const float* __restrict__ c_b,
    const unsigned short* __restrict__ whi,
    const float* __restrict__ bc,
    float* __restrict__ out, int N)
{
    // double-buffered HALF-matrix weight stage (2 x 16 KB) -> 52.7 KB total LDS
    __shared__ __align__(16) unsigned short WL[2][8192];
    // per-wave bf16 scratch: rh -> h' -> out staging
    __shared__ __align__(16) unsigned short Sr_all[NW][NPW][SRP];
    __shared__ float bias_s[4][Hd];
    __shared__ int lo_all[NW][NPW];
    __shared__ int hi_all[NW][NPW];

    const int tid = threadIdx.x;
    const int wid = tid >> 6;
    const int l   = tid & 63;
    const int lr  = l & 15;
    const int lg  = l >> 4;
    const int n0  = (blockIdx.x * NW + wid) * NPW;

    unsigned short (*Sr)[SRP] = Sr_all[wid];
    int* loL = lo_all[wid];
    int* hiL = hi_all[wid];

    if (tid < Hd){
        bias_s[0][tid] = r_b[tid];
        bias_s[1][tid] = u_b[tid];
        bias_s[2][tid] = c_b[tid];
        bias_s[3][tid] = bc[tid];
    }

    // stage one 16KB half-matrix: 16 chunks of 1KB; wave covers chunks it*4+wid
    #define STAGE_H(mat, half, buf)                                              \
        {                                                                        \
            const unsigned short* msrc = whi + (size_t)(mat) * 16384 + (half) * 8192; \
            _Pragma("unroll")                                                    \
            for (int it = 0; it < 4; ++it){                                      \
                const int chunk = it * 4 + wid;                                  \
                gload_lds16(msrc + chunk * 512 + l * 8, &WL[buf][chunk * 512]);  \
            }                                                                    \
        }

    // one pipeline phase: drain prev loads, prefetch next half, compute current
    #define PHASE(ACC, A0, A1, DO, SM, SH)                                       \
        __syncthreads();                                                         \
        if (DO) STAGE_H(SM, SH, cur ^ 1);                                        \
        _Pragma("unroll")                                                        \
        for (int nc = 0; nc < 8; ++nc){                                          \
            s16x8 b0 = BF_LDS(0, nc);                                            \
            s16x8 b1 = BF_LDS(1, nc);                                            \
            MM1(ACC[nc], A0, b0);                                                \
            MM1(ACC[nc], A1, b1);                                                \
            if ((nc & 3) == 3) __builtin_amdgcn_sched_barrier(0);                \
        }                                                                        \
        cur ^= 1;

    // persistent register state
    f32x4 hD[8];              // h f32 in D-layout: row lg*4+i, col nc*16+lr
    s16x8 ah[4];              // h A-frags bf16 (row lr, k = kc*32+lg*8+j); h(t=0)=0
    #pragma unroll
    for (int nc = 0; nc < 8; ++nc) hD[nc] = (f32x4){0.f, 0.f, 0.f, 0.f};
    #pragma unroll
    for (int kc = 0; kc < 4; ++kc) ah[kc] = (s16x8)0;
    s16x8 xh[4], rhh[4];

    unsigned cur = 0;
    STAGE_H(0, 0, 0);         // prologue: r_whh half0 into buf0

    #pragma unroll 1
    for (int t = 0; t < Rr; ++t){
        // ---- output-row ranges + x A-frags (overlap the in-flight stage) ----
        if (l < NPW){
            int n = n0 + l, lo = 0, hi = 0;
            if (n < N){
                int F = (n * Rr + t) * Ll;
                lo = lower_bound_i32(valid_idx, nv, F);
                hi = lower_bound_i32(valid_idx, nv, F + Ll);
            }
            loL[l] = lo; hiL[l] = hi;
        }
        {
            int nn = n0 + lr; if (nn > N - 1) nn = N - 1;
            const float* xp = x_rank + ((size_t)nn * Rr + t) * Hd;
            #pragma unroll
            for (int kc = 0; kc < 4; ++kc)
                xh[kc] = cvt8(xp + kc * 32 + lg * 8);
        }

        // ==== R: accR = h@r_whh + x@r_wxh ====
        f32x4 accR[8];
        #pragma unroll
        for (int nc = 0; nc < 8; ++nc) accR[nc] = (f32x4){0.f, 0.f, 0.f, 0.f};
        PHASE(accR, ah[0], ah[1], 1, 0, 1);   // P1: mat0.h0 ; stage mat0.h1
        PHASE(accR, ah[2], ah[3], 1, 2, 0);   // P2: mat0.h1 ; stage mat2.h0
        PHASE(accR, xh[0], xh[1], 1, 2, 1);   // P3: mat2.h0 ; stage mat2.h1
        PHASE(accR, xh[2], xh[3], 1, 1, 0);   // P4: mat2.h1 ; stage mat1.h0
        // R-activation: Sr = bf16(sigmoid(accR+rb) * h)   (overlaps mat1.h0 fill)
        #pragma unroll
        for (int nc = 0; nc < 8; ++nc){
            const float rbc = bias_s[0][nc * 16 + lr];
            #pragma unroll
            for (int i = 0; i < 4; ++i){
                float r = 1.f / (1.f + __expf(-(accR[nc][i] + rbc)));
                Sr[lg * 4 + i][nc * 16 + lr] = f2bf(r * hD[nc][i]);
            }
        }

        // ==== Z: accZ = h@u_whh + x@u_wxh ====
        f32x4 accZ[8];
        #pragma unroll
        for (int nc = 0; nc < 8; ++nc) accZ[nc] = (f32x4){0.f, 0.f, 0.f, 0.f};
        PHASE(accZ, ah[0], ah[1], 1, 1, 1);   // P5: mat1.h0 ; stage mat1.h1
        PHASE(accZ, ah[2], ah[3], 1, 3, 0);   // P6: mat1.h1 ; stage mat3.h0
        PHASE(accZ, xh[0], xh[1], 1, 3, 1);   // P7: mat3.h0 ; stage mat3.h1
        PHASE(accZ, xh[2], xh[3], 1, 4, 0);   // P8: mat3.h1 ; stage mat4.h0
        // Z-activation (z stays in accZ); rh frags from Sr (same-wave in-order)
        #pragma unroll
        for (int nc = 0; nc < 8; ++nc){
            const float ubc = bias_s[1][nc * 16 + lr];
            #pragma unroll
            for (int i = 0; i < 4; ++i)
                accZ[nc][i] = 1.f / (1.f + __expf(-(accZ[nc][i] + ubc)));
        }
        #pragma unroll
        for (int kc = 0; kc < 4; ++kc)
            rhh[kc] = *(const s16x8*)&Sr[lr][kc * 32 + lg * 8];

        // ==== C: accC = (r*h)@c_whh + x@c_wxh ====
        f32x4 accC[8];
        #pragma unroll
        for (int nc = 0; nc < 8; ++nc) accC[nc] = (f32x4){0.f, 0.f, 0.f, 0.f};
        PHASE(accC, rhh[0], rhh[1], 1, 4, 1); // P9:  mat4.h0 ; stage mat4.h1
        PHASE(accC, rhh[2], rhh[3], 1, 5, 0); // P10: mat4.h1 ; stage mat5.h0
        PHASE(accC, xh[0],  xh[1],  1, 5, 1); // P11: mat5.h0 ; stage mat5.h1
        PHASE(accC, xh[2],  xh[3],  1, 6, 0); // P12: mat5.h1 ; stage mat6.h0
        // C-activation + h-update; Sr = bf16(h'); refresh ah for O and next t
        #pragma unroll
        for (int nc = 0; nc < 8; ++nc){
            const float cbc = bias_s[2][nc * 16 + lr];
            #pragma unroll
            for (int i = 0; i < 4; ++i){
                float e = __expf(2.f * (accC[nc][i] + cbc));
                float c = 1.f - 2.f / (e + 1.f);     // tanh, saturates correctly
                float ho = hD[nc][i];
                float hn = ho + accZ[nc][i] * (c - ho);
                hD[nc][i] = hn;
                Sr[lg * 4 + i][nc * 16 + lr] = f2bf(hn);
            }
        }
        #pragma unroll
        for (int kc = 0; kc < 4; ++kc)
            ah[kc] = *(const s16x8*)&Sr[lr][kc * 32 + lg * 8];

        // ==== O: accO = h'@McT ====
        f32x4 accO[8];
        #pragma unroll
        for (int nc = 0; nc < 8; ++nc) accO[nc] = (f32x4){0.f, 0.f, 0.f, 0.f};
        PHASE(accO, ah[0], ah[1], 1, 6, 1);            // P13: mat6.h0 ; stage mat6.h1
        const int more = (t < Rr - 1);
        PHASE(accO, ah[2], ah[3], more, 0, 0);         // P14: mat6.h1 ; stage next-t mat0.h0
        // O staging + coalesced scatter epilogue (overlaps next-t stage fill)
        #pragma unroll
        for (int nc = 0; nc < 8; ++nc){
            const float obc = bias_s[3][nc * 16 + lr];
            #pragma unroll
            for (int i = 0; i < 4; ++i)
                Sr[lg * 4 + i][nc * 16 + lr] = f2bf(accO[nc][i] + obc);
        }
        #pragma unroll
        for (int m = 0; m < 8; ++m){
            const int row = m * 2 + (l >> 5);
            const int c4  = (l & 31) * 4;
            const uint2 u = *(const uint2*)&Sr[row][c4];
            float4 v = { bf2f((unsigned short)(u.x & 0xffff)),
                         bf2f((unsigned short)(u.x >> 16)),
                         bf2f((unsigned short)(u.y & 0xffff)),
                         bf2f((unsigned short)(u.y >> 16)) };
            const int lo = loL[row], hi = hiL[row];
            for (int rr = lo; rr < hi; ++rr)
                *(float4*)(out + (size_t)rr * Hd + c4) = v;
        }
    }
    #undef PHASE
    #undef STAGE_H
}

__global__ void he_order_kernel(const int* __restrict__ he_order,
                                float* __restrict__ out_tail, int nv)
{
    const int i = blockIdx.x * 256 + threadIdx.x;
    if (i < nv) out_tail[i] = (float)he_order[i];
}

extern "C" void kernel_launch(void* const* d_in, const int* in_sizes, int n_in,
                              void* d_out, int out_size, void* d_ws, size_t ws_size,
                              hipStream_t stream)
{
    const float* x_rank    = (const float*)d_in[0];
    // d_in[1] he_features, d_in[2] he_idx: dead (softmax over singleton axis == 1)
    const int*   valid_idx = (const int*)d_in[3];
    const int*   he_order  = (const int*)d_in[4];
    const float* r_whh = (const float*)d_in[5];
    const float* r_wxh = (const float*)d_in[6];
    const float* r_b   = (const float*)d_in[7];
    const float* u_whh = (const float*)d_in[8];
    const float* u_wxh = (const float*)d_in[9];
    const float* u_b   = (const float*)d_in[10];
    const float* c_whh = (const float*)d_in[11];
    const float* c_wxh = (const float*)d_in[12];
    const float* c_b   = (const float*)d_in[13];
    const float* in_proj_w = (const float*)d_in[14];
    const float* in_proj_b = (const float*)d_in[15];
    const float* out_w     = (const float*)d_in[16];
    const float* out_b     = (const float*)d_in[17];

    const int nv = in_sizes[3];
    const int N  = in_sizes[0] / (Rr * Hd);

    // workspace layout
    float* McT = (float*)d_ws;                         // 16384 f32
    float* bc  = McT + Hd * Hd;                        // 128 f32
    unsigned short* whi = (unsigned short*)(bc + Hd);  // 7*16384 u16

    float* out_f    = (float*)d_out;
    float* out_tail = out_f + (size_t)nv * Hd;

    fold_proj_kernel<<<Hd, Hd, 0, stream>>>(in_proj_w, in_proj_b, out_w, out_b, McT, bc);
    pack_kernel<<<dim3(32, 7), 64, 0, stream>>>(r_whh, u_whh, r_wxh, u_wxh, c_whh, c_wxh,
                                                McT, whi);

    const int nodes_per_block = NW * NPW;  // 64
    const int nblocks = (N + nodes_per_block - 1) / nodes_per_block;  // 469
    gru_mfma_kernel<<<nblocks, 256, 0, stream>>>(
        x_rank, valid_idx, nv, r_b, u_b, c_b, whi, bc, out_f, N);

    he_order_kernel<<<(nv + 255) / 256, 256, 0, stream>>>(he_order, out_tail, nv);
}

// Round 13
// 160.038 us; speedup vs baseline: 1.2054x; 1.2054x over previous
//
#include <hip/hip_runtime.h>
#include <math.h>

#define Hd 128
#define Rr 3
#define Ll 4
#define NPW 16   // nodes (M-rows) per wave
#define NW  4    // waves per block (256 threads); 469 blocks -> ~2 blocks/CU
#define SRP 136  // Sr row pitch in bf16 elems (272 B: 16-B aligned, 2-way-bank-benign)

typedef float f32x4 __attribute__((ext_vector_type(4)));
typedef short s16x8 __attribute__((ext_vector_type(8)));

__device__ __forceinline__ unsigned short f2bf(float f){
    unsigned u = __float_as_uint(f);
    return (unsigned short)((u + 0x7FFFu + ((u >> 16) & 1u)) >> 16);
}
__device__ __forceinline__ float bf2f(unsigned short h){
    return __uint_as_float(((unsigned)h) << 16);
}
// convert 8 consecutive f32 (global) -> bf16 A-fragment
__device__ __forceinline__ s16x8 cvt8(const float* p){
    float4 a = *(const float4*)p;
    float4 b = *(const float4*)(p + 4);
    float v[8] = {a.x, a.y, a.z, a.w, b.x, b.y, b.z, b.w};
    s16x8 r;
    #pragma unroll
    for (int j = 0; j < 8; ++j) r[j] = (short)f2bf(v[j]);
    return r;
}
__device__ __forceinline__ int lower_bound_i32(const int* __restrict__ a, int n, int key){
    int lo = 0, hi = n;
    while (lo < hi){
        int mid = (lo + hi) >> 1;
        if (a[mid] < key) lo = mid + 1; else hi = mid;
    }
    return lo;
}

// async global->LDS, 16B per lane; LDS dest = uniform base + lane*16
__device__ __forceinline__ void gload_lds16(const unsigned short* g, unsigned short* l){
    __builtin_amdgcn_global_load_lds(
        (const __attribute__((address_space(1))) void*)g,
        (__attribute__((address_space(3))) void*)l, 16, 0, 0);
}

// ---- McT = out_w @ wv (folded), bc = out_w @ bv + out_b  (verified r1-r12) ----
__global__ void fold_proj_kernel(const float* __restrict__ in_proj_w,
                                 const float* __restrict__ in_proj_b,
                                 const float* __restrict__ out_w,
                                 const float* __restrict__ out_b,
                                 float* __restrict__ McT,
                                 float* __restrict__ bc)
{
    const int i = blockIdx.x;   // k index
    const int j = threadIdx.x;  // n index
    float acc = 0.f;
    for (int k = 0; k < Hd; ++k)
        acc = fmaf(out_w[j * Hd + k], in_proj_w[(2 * Hd + k) * Hd + i], acc);
    McT[i * Hd + j] = acc;
    if (i == 0){
        float b = out_b[j];
        for (int k = 0; k < Hd; ++k)
            b = fmaf(out_w[j * Hd + k], in_proj_b[2 * Hd + k], b);
        bc[j] = b;
    }
}

// ---- quantize weights to bf16 MFMA B-fragments (verified r4-r12) ----
// frag elem j of lane l at (mat,kc,nc):  W[kc*32 + (l>>4)*8 + j][nc*16 + (l&15)]
__global__ void pack_kernel(const float* __restrict__ r_whh, const float* __restrict__ u_whh,
                            const float* __restrict__ r_wxh, const float* __restrict__ u_wxh,
                            const float* __restrict__ c_whh, const float* __restrict__ c_wxh,
                            const float* __restrict__ McT,
                            unsigned short* __restrict__ whi)
{
    const int mat  = blockIdx.y;   // 0..6
    const int tile = blockIdx.x;   // 0..31 : kc = tile>>3, nc = tile&7
    const int l    = threadIdx.x;  // 0..63
    const float* W;
    switch (mat){
        case 0: W = r_whh; break;  case 1: W = u_whh; break;
        case 2: W = r_wxh; break;  case 3: W = u_wxh; break;
        case 4: W = c_whh; break;  case 5: W = c_wxh; break;
        default: W = McT;
    }
    const int kc = tile >> 3, nc = tile & 7;
    const int kbase = kc * 32 + (l >> 4) * 8;
    const int n = nc * 16 + (l & 15);
    const size_t obase = ((size_t)(mat * 32 + tile) * 64 + l) * 8;
    #pragma unroll
    for (int j = 0; j < 8; ++j)
        whi[obase + j] = f2bf(W[(kbase + j) * Hd + n]);
}

// B-frag read from current half-buffer: kk = local kc (0/1), nc 0..7
#define BF_LDS(kk, nc) (*(const s16x8*)&WL[cur][(((kk) * 8 + (nc)) * 64 + l) * 8])

#define MM1(acc, AH, BH)                                                  \
    acc = __builtin_amdgcn_mfma_f32_16x16x32_bf16(AH, BH, acc, 0, 0, 0);

__global__ __launch_bounds__(256, 1) void gru_mfma_kernel(
    const float* __restrict__ x_rank,
    const int* __restrict__ valid_idx, int nv,
    const float* __restrict__ r_b, const float* __restrict__ u_b, const float* __restrict__ c_b,
    const unsigned short* __restrict__ whi,
    const float* __restrict__ bc,
    float* __restrict__ out, int N)
{
    // double-buffered HALF-matrix weight stage (2 x 16 KB) -> 52.7 KB total LDS
    __shared__ __align__(16) unsigned short WL[2][8192];
    // per-wave bf16 scratch: rh -> h' -> out staging
    __shared__ __align__(16) unsigned short Sr_all[NW][NPW][SRP];
    __shared__ float bias_s[4][Hd];
    __shared__ int lo_all[NW][NPW];
    __shared__ int hi_all[NW][NPW];

    const int tid = threadIdx.x;
    const int wid = tid >> 6;
    const int l   = tid & 63;
    const int lr  = l & 15;
    const int lg  = l >> 4;
    const int n0  = (blockIdx.x * NW + wid) * NPW;

    unsigned short (*Sr)[SRP] = Sr_all[wid];
    int* loL = lo_all[wid];
    int* hiL = hi_all[wid];

    if (tid < Hd){
        bias_s[0][tid] = r_b[tid];
        bias_s[1][tid] = u_b[tid];
        bias_s[2][tid] = c_b[tid];
        bias_s[3][tid] = bc[tid];
    }

    // stage one 16KB half-matrix: 16 chunks of 1KB; wave covers chunks it*4+wid
    #define STAGE_H(mat, half, buf)                                              \
        {                                                                        \
            const unsigned short* msrc = whi + (size_t)(mat) * 16384 + (half) * 8192; \
            _Pragma("unroll")                                                    \
            for (int it = 0; it < 4; ++it){                                      \
                const int chunk = it * 4 + wid;                                  \
                gload_lds16(msrc + chunk * 512 + l * 8, &WL[buf][chunk * 512]);  \
            }                                                                    \
        }

    // one pipeline phase: drain prev loads, prefetch next half, compute current
    #define PHASE(ACC, A0, A1, DO, SM, SH)                                       \
        __syncthreads();                                                         \
        if (DO) STAGE_H(SM, SH, cur ^ 1);                                        \
        _Pragma("unroll")                                                        \
        for (int nc = 0; nc < 8; ++nc){                                          \
            s16x8 b0 = BF_LDS(0, nc);                                            \
            s16x8 b1 = BF_LDS(1, nc);                                            \
            MM1(ACC[nc], A0, b0);                                                \
            MM1(ACC[nc], A1, b1);                                                \
            if ((nc & 3) == 3) __builtin_amdgcn_sched_barrier(0);                \
        }                                                                        \
        cur ^= 1;

    // persistent register state
    f32x4 hD[8];              // h f32 in D-layout: row lg*4+i, col nc*16+lr
    s16x8 ah[4];              // h A-frags bf16 (row lr, k = kc*32+lg*8+j); h(t=0)=0
    #pragma unroll
    for (int nc = 0; nc < 8; ++nc) hD[nc] = (f32x4){0.f, 0.f, 0.f, 0.f};
    #pragma unroll
    for (int kc = 0; kc < 4; ++kc) ah[kc] = (s16x8)0;
    s16x8 xh[4], rhh[4];

    unsigned cur = 0;
    STAGE_H(0, 0, 0);         // prologue: r_whh half0 into buf0

    #pragma unroll 1
    for (int t = 0; t < Rr; ++t){
        // ---- output-row ranges + x A-frags (overlap the in-flight stage) ----
        if (l < NPW){
            int n = n0 + l, lo = 0, hi = 0;
            if (n < N){
                int F = (n * Rr + t) * Ll;
                lo = lower_bound_i32(valid_idx, nv, F);
                hi = lower_bound_i32(valid_idx, nv, F + Ll);
            }
            loL[l] = lo; hiL[l] = hi;
        }
        {
            int nn = n0 + lr; if (nn > N - 1) nn = N - 1;
            const float* xp = x_rank + ((size_t)nn * Rr + t) * Hd;
            #pragma unroll
            for (int kc = 0; kc < 4; ++kc)
                xh[kc] = cvt8(xp + kc * 32 + lg * 8);
        }

        // ==== R: accR = h@r_whh + x@r_wxh ====
        f32x4 accR[8];
        #pragma unroll
        for (int nc = 0; nc < 8; ++nc) accR[nc] = (f32x4){0.f, 0.f, 0.f, 0.f};
        PHASE(accR, ah[0], ah[1], 1, 0, 1);   // P1: mat0.h0 ; stage mat0.h1
        PHASE(accR, ah[2], ah[3], 1, 2, 0);   // P2: mat0.h1 ; stage mat2.h0
        PHASE(accR, xh[0], xh[1], 1, 2, 1);   // P3: mat2.h0 ; stage mat2.h1
        PHASE(accR, xh[2], xh[3], 1, 1, 0);   // P4: mat2.h1 ; stage mat1.h0
        // R-activation: Sr = bf16(sigmoid(accR+rb) * h)   (overlaps mat1.h0 fill)
        #pragma unroll
        for (int nc = 0; nc < 8; ++nc){
            const float rbc = bias_s[0][nc * 16 + lr];
            #pragma unroll
            for (int i = 0; i < 4; ++i){
                float r = 1.f / (1.f + __expf(-(accR[nc][i] + rbc)));
                Sr[lg * 4 + i][nc * 16 + lr] = f2bf(r * hD[nc][i]);
            }
        }

        // ==== Z: accZ = h@u_whh + x@u_wxh ====
        f32x4 accZ[8];
        #pragma unroll
        for (int nc = 0; nc < 8; ++nc) accZ[nc] = (f32x4){0.f, 0.f, 0.f, 0.f};
        PHASE(accZ, ah[0], ah[1], 1, 1, 1);   // P5: mat1.h0 ; stage mat1.h1
        PHASE(accZ, ah[2], ah[3], 1, 3, 0);   // P6: mat1.h1 ; stage mat3.h0
        PHASE(accZ, xh[0], xh[1], 1, 3, 1);   // P7: mat3.h0 ; stage mat3.h1
        PHASE(accZ, xh[2], xh[3], 1, 4, 0);   // P8: mat3.h1 ; stage mat4.h0
        // Z-activation (z stays in accZ); rh frags from Sr (same-wave in-order)
        #pragma unroll
        for (int nc = 0; nc < 8; ++nc){
            const float ubc = bias_s[1][nc * 16 + lr];
            #pragma unroll
            for (int i = 0; i < 4; ++i)
                accZ[nc][i] = 1.f / (1.f + __expf(-(accZ[nc][i] + ubc)));
        }
        #pragma unroll
        for (int kc = 0; kc < 4; ++kc)
            rhh[kc] = *(const s16x8*)&Sr[lr][kc * 32 + lg * 8];

        // ==== C: accC = (r*h)@c_whh + x@c_wxh ====
        f32x4 accC[8];
        #pragma unroll
        for (int nc = 0; nc < 8; ++nc) accC[nc] = (f32x4){0.f, 0.f, 0.f, 0.f};
        PHASE(accC, rhh[0], rhh[1], 1, 4, 1); // P9:  mat4.h0 ; stage mat4.h1
        PHASE(accC, rhh[2], rhh[3], 1, 5, 0); // P10: mat4.h1 ; stage mat5.h0
        PHASE(accC, xh[0],  xh[1],  1, 5, 1); // P11: mat5.h0 ; stage mat5.h1
        PHASE(accC, xh[2],  xh[3],  1, 6, 0); // P12: mat5.h1 ; stage mat6.h0
        // C-activation + h-update; Sr = bf16(h'); refresh ah for O and next t
        #pragma unroll
        for (int nc = 0; nc < 8; ++nc){
            const float cbc = bias_s[2][nc * 16 + lr];
            #pragma unroll
            for (int i = 0; i < 4; ++i){
                float e = __expf(2.f * (accC[nc][i] + cbc));
                float c = 1.f - 2.f / (e + 1.f);     // tanh, saturates correctly
                float ho = hD[nc][i];
                float hn = ho + accZ[nc][i] * (c - ho);
                hD[nc][i] = hn;
                Sr[lg * 4 + i][nc * 16 + lr] = f2bf(hn);
            }
        }
        #pragma unroll
        for (int kc = 0; kc < 4; ++kc)
            ah[kc] = *(const s16x8*)&Sr[lr][kc * 32 + lg * 8];

        // ==== O: accO = h'@McT ====
        f32x4 accO[8];
        #pragma unroll
        for (int nc = 0; nc < 8; ++nc) accO[nc] = (f32x4){0.f, 0.f, 0.f, 0.f};
        PHASE(accO, ah[0], ah[1], 1, 6, 1);            // P13: mat6.h0 ; stage mat6.h1
        const int more = (t < Rr - 1);
        PHASE(accO, ah[2], ah[3], more, 0, 0);         // P14: mat6.h1 ; stage next-t mat0.h0
        // O staging + coalesced scatter epilogue (overlaps next-t stage fill)
        #pragma unroll
        for (int nc = 0; nc < 8; ++nc){
            const float obc = bias_s[3][nc * 16 + lr];
            #pragma unroll
            for (int i = 0; i < 4; ++i)
                Sr[lg * 4 + i][nc * 16 + lr] = f2bf(accO[nc][i] + obc);
        }
        #pragma unroll
        for (int m = 0; m < 8; ++m){
            const int row = m * 2 + (l >> 5);
            const int c4  = (l & 31) * 4;
            const uint2 u = *(const uint2*)&Sr[row][c4];
            float4 v = { bf2f((unsigned short)(u.x & 0xffff)),
                         bf2f((unsigned short)(u.x >> 16)),
                         bf2f((unsigned short)(u.y & 0xffff)),
                         bf2f((unsigned short)(u.y >> 16)) };
            const int lo = loL[row], hi = hiL[row];
            for (int rr = lo; rr < hi; ++rr)
                *(float4*)(out + (size_t)rr * Hd + c4) = v;
        }
    }
    #undef PHASE
    #undef STAGE_H
}

__global__ void he_order_kernel(const int* __restrict__ he_order,
                                float* __restrict__ out_tail, int nv)
{
    const int i = blockIdx.x * 256 + threadIdx.x;
    if (i < nv) out_tail[i] = (float)he_order[i];
}

extern "C" void kernel_launch(void* const* d_in, const int* in_sizes, int n_in,
                              void* d_out, int out_size, void* d_ws, size_t ws_size,
                              hipStream_t stream)
{
    const float* x_rank    = (const float*)d_in[0];
    // d_in[1] he_features, d_in[2] he_idx: dead (softmax over singleton axis == 1)
    const int*   valid_idx = (const int*)d_in[3];
    const int*   he_order  = (const int*)d_in[4];
    const float* r_whh = (const float*)d_in[5];
    const float* r_wxh = (const float*)d_in[6];
    const float* r_b   = (const float*)d_in[7];
    const float* u_whh = (const float*)d_in[8];
    const float* u_wxh = (const float*)d_in[9];
    const float* u_b   = (const float*)d_in[10];
    const float* c_whh = (const float*)d_in[11];
    const float* c_wxh = (const float*)d_in[12];
    const float* c_b   = (const float*)d_in[13];
    const float* in_proj_w = (const float*)d_in[14];
    const float* in_proj_b = (const float*)d_in[15];
    const float* out_w     = (const float*)d_in[16];
    const float* out_b     = (const float*)d_in[17];

    const int nv = in_sizes[3];
    const int N  = in_sizes[0] / (Rr * Hd);

    // workspace layout
    float* McT = (float*)d_ws;                         // 16384 f32
    float* bc  = McT + Hd * Hd;                        // 128 f32
    unsigned short* whi = (unsigned short*)(bc + Hd);  // 7*16384 u16

    float* out_f    = (float*)d_out;
    float* out_tail = out_f + (size_t)nv * Hd;

    fold_proj_kernel<<<Hd, Hd, 0, stream>>>(in_proj_w, in_proj_b, out_w, out_b, McT, bc);
    pack_kernel<<<dim3(32, 7), 64, 0, stream>>>(r_whh, u_whh, r_wxh, u_wxh, c_whh, c_wxh,
                                                McT, whi);

    const int nodes_per_block = NW * NPW;  // 64
    const int nblocks = (N + nodes_per_block - 1) / nodes_per_block;  // 469
    gru_mfma_kernel<<<nblocks, 256, 0, stream>>>(
        x_rank, valid_idx, nv, r_b, u_b, c_b, whi, bc, out_f, N);

    he_order_kernel<<<(nv + 255) / 256, 256, 0, stream>>>(he_order, out_tail, nv);
}

// Round 14
// 110.627 us; speedup vs baseline: 1.7438x; 1.4466x over previous
//
#include <hip/hip_runtime.h>
#include <math.h>

#define Hd 128
#define Rr 3
#define Ll 4
#define NPW 16   // nodes (M-rows) per wave
#define NW  8    // waves per block (512 threads)
#define SRP 136  // Sr row pitch in bf16 elems (272 B: 16-B aligned, bank-benign)

typedef float f32x4 __attribute__((ext_vector_type(4)));
typedef short s16x8 __attribute__((ext_vector_type(8)));

__device__ __forceinline__ unsigned short f2bf(float f){
    unsigned u = __float_as_uint(f);
    return (unsigned short)((u + 0x7FFFu + ((u >> 16) & 1u)) >> 16);
}
__device__ __forceinline__ float bf2f(unsigned short h){
    return __uint_as_float(((unsigned)h) << 16);
}
// convert 8 consecutive f32 (global) -> bf16 A-fragment
__device__ __forceinline__ s16x8 cvt8(const float* p){
    float4 a = *(const float4*)p;
    float4 b = *(const float4*)(p + 4);
    float v[8] = {a.x, a.y, a.z, a.w, b.x, b.y, b.z, b.w};
    s16x8 r;
    #pragma unroll
    for (int j = 0; j < 8; ++j) r[j] = (short)f2bf(v[j]);
    return r;
}
__device__ __forceinline__ int lower_bound_i32(const int* __restrict__ a, int n, int key){
    int lo = 0, hi = n;
    while (lo < hi){
        int mid = (lo + hi) >> 1;
        if (a[mid] < key) lo = mid + 1; else hi = mid;
    }
    return lo;
}

// async global->LDS, 16B per lane; LDS dest = uniform base + lane*16
__device__ __forceinline__ void gload_lds16(const unsigned short* g, unsigned short* l){
    __builtin_amdgcn_global_load_lds(
        (const __attribute__((address_space(1))) void*)g,
        (__attribute__((address_space(3))) void*)l, 16, 0, 0);
}

// ---- McT = out_w @ wv (folded), bc = out_w @ bv + out_b  (verified r1-r13) ----
__global__ void fold_proj_kernel(const float* __restrict__ in_proj_w,
                                 const float* __restrict__ in_proj_b,
                                 const float* __restrict__ out_w,
                                 const float* __restrict__ out_b,
                                 float* __restrict__ McT,
                                 float* __restrict__ bc)
{
    const int i = blockIdx.x;   // k index
    const int j = threadIdx.x;  // n index
    float acc = 0.f;
    for (int k = 0; k < Hd; ++k)
        acc = fmaf(out_w[j * Hd + k], in_proj_w[(2 * Hd + k) * Hd + i], acc);
    McT[i * Hd + j] = acc;
    if (i == 0){
        float b = out_b[j];
        for (int k = 0; k < Hd; ++k)
            b = fmaf(out_w[j * Hd + k], in_proj_b[2 * Hd + k], b);
        bc[j] = b;
    }
}

// ---- quantize weights to bf16 MFMA B-fragments (verified r4-r13) ----
// frag elem j of lane l at (mat,kc,nc):  W[kc*32 + (l>>4)*8 + j][nc*16 + (l&15)]
__global__ void pack_kernel(const float* __restrict__ r_whh, const float* __restrict__ u_whh,
                            const float* __restrict__ r_wxh, const float* __restrict__ u_wxh,
                            const float* __restrict__ c_whh, const float* __restrict__ c_wxh,
                            const float* __restrict__ McT,
                            unsigned short* __restrict__ whi)
{
    const int mat  = blockIdx.y;   // 0..6
    const int tile = blockIdx.x;   // 0..31 : kc = tile>>3, nc = tile&7
    const int l    = threadIdx.x;  // 0..63
    const float* W;
    switch (mat){
        case 0: W = r_whh; break;  case 1: W = u_whh; break;
        case 2: W = r_wxh; break;  case 3: W = u_wxh; break;
        case 4: W = c_whh; break;  case 5: W = c_wxh; break;
        default: W = McT;
    }
    const int kc = tile >> 3, nc = tile & 7;
    const int kbase = kc * 32 + (l >> 4) * 8;
    const int n = nc * 16 + (l & 15);
    const size_t obase = ((size_t)(mat * 32 + tile) * 64 + l) * 8;
    #pragma unroll
    for (int j = 0; j < 8; ++j)
        whi[obase + j] = f2bf(W[(kbase + j) * Hd + n]);
}

// B-frag read from current LDS weight buffer (ds_read_b128, contiguous per wave)
#define BF_LDS(kc, nc) (*(const s16x8*)&WL[cur][(((kc) * 8 + (nc)) * 64 + l) * 8])

#define MM1(acc, AH, BH)                                                  \
    acc = __builtin_amdgcn_mfma_f32_16x16x32_bf16(AH, BH, acc, 0, 0, 0);

__global__ __launch_bounds__(512, 1) void gru_mfma_kernel(
    const float* __restrict__ x_rank,
    const int* __restrict__ valid_idx, int nv,
    const float* __restrict__ r_b, const float* __restrict__ u_b, const float* __restrict__ c_b,
    const unsigned short* __restrict__ whi,
    const float* __restrict__ bc,
    float* __restrict__ out, int N)
{
    // double-buffered block-shared weight stage (2 x 32 KB)
    __shared__ __align__(16) unsigned short WL[2][16384];
    // per-wave bf16 scratch: rh -> h' -> out staging
    __shared__ __align__(16) unsigned short Sr_all[NW][NPW][SRP];
    __shared__ float bias_s[4][Hd];
    __shared__ int lo_all[NW][NPW];
    __shared__ int hi_all[NW][NPW];

    const int tid = threadIdx.x;
    const int wid = tid >> 6;
    const int l   = tid & 63;
    const int lr  = l & 15;
    const int lg  = l >> 4;
    const int n0  = (blockIdx.x * NW + wid) * NPW;

    unsigned short (*Sr)[SRP] = Sr_all[wid];
    int* loL = lo_all[wid];
    int* hiL = hi_all[wid];

    if (tid < Hd){
        bias_s[0][tid] = r_b[tid];
        bias_s[1][tid] = u_b[tid];
        bias_s[2][tid] = c_b[tid];
        bias_s[3][tid] = bc[tid];
    }

    // stage one 32KB matrix into buffer b: 32 chunks of 1KB, wave covers it*8+wid
    #define STAGE_MAT(mat, b)                                                    \
        {                                                                        \
            const unsigned short* msrc = whi + (size_t)(mat) * 16384;            \
            _Pragma("unroll")                                                    \
            for (int it = 0; it < 4; ++it){                                      \
                const int chunk = it * 8 + wid;                                  \
                gload_lds16(msrc + chunk * 512 + l * 8, &WL[b][chunk * 512]);    \
            }                                                                    \
        }

    // persistent register state
    f32x4 hD[8];              // h f32 in D-layout: row lg*4+i, col nc*16+lr (exact state)
    s16x8 ah[4];              // h A-frags bf16 (row lr, k = kc*32+lg*8+j); h(t=0)=0
    #pragma unroll
    for (int nc = 0; nc < 8; ++nc) hD[nc] = (f32x4){0.f, 0.f, 0.f, 0.f};
    #pragma unroll
    for (int kc = 0; kc < 4; ++kc) ah[kc] = (s16x8)0;
    s16x8 xh[4], rhh[4];

    unsigned cur = 0;
    STAGE_MAT(0, 0);          // prologue: r_whh into buf0

    #pragma unroll 1
    for (int t = 0; t < Rr; ++t){
        // ---- output-row ranges + x A-frags (overlap in-flight stage) ----
        if (l < NPW){
            int n = n0 + l, lo = 0, hi = 0;
            if (n < N){
                int F = (n * Rr + t) * Ll;
                lo = lower_bound_i32(valid_idx, nv, F);
                hi = lower_bound_i32(valid_idx, nv, F + Ll);
            }
            loL[l] = lo; hiL[l] = hi;
        }
        {
            int nn = n0 + lr; if (nn > N - 1) nn = N - 1;
            const float* xp = x_rank + ((size_t)nn * Rr + t) * Hd;
            #pragma unroll
            for (int kc = 0; kc < 4; ++kc)
                xh[kc] = cvt8(xp + kc * 32 + lg * 8);
        }

        f32x4 accR[8], accZ[8], accC[8];

        // ==== S1: [r_whh ready] issue r_wxh; accR = h @ r_whh ====
        __syncthreads();
        STAGE_MAT(2, cur ^ 1);
        #pragma unroll
        for (int nc = 0; nc < 8; ++nc){
            accR[nc] = (f32x4){0.f, 0.f, 0.f, 0.f};
            #pragma unroll
            for (int kc = 0; kc < 4; ++kc){ s16x8 b = BF_LDS(kc, nc); MM1(accR[nc], ah[kc], b); }
            if ((nc & 3) == 3) __builtin_amdgcn_sched_barrier(0);
        }
        cur ^= 1;

        // ==== S2: [r_wxh ready] issue u_whh; accR += x @ r_wxh (act deferred) ====
        __syncthreads();
        STAGE_MAT(1, cur ^ 1);
        #pragma unroll
        for (int nc = 0; nc < 8; ++nc){
            #pragma unroll
            for (int kc = 0; kc < 4; ++kc){ s16x8 b = BF_LDS(kc, nc); MM1(accR[nc], xh[kc], b); }
            if ((nc & 3) == 3) __builtin_amdgcn_sched_barrier(0);
        }
        cur ^= 1;

        // ==== S3: [u_whh ready] issue u_wxh; DEFERRED R-act ∥ accZ = h @ u_whh ====
        __syncthreads();
        STAGE_MAT(3, cur ^ 1);
        // deferred R-activation: interleaves with the ds_reads below (no fence)
        #pragma unroll
        for (int nc = 0; nc < 8; ++nc){
            const float rbc = bias_s[0][nc * 16 + lr];
            #pragma unroll
            for (int i = 0; i < 4; ++i){
                float r = 1.f / (1.f + __expf(-(accR[nc][i] + rbc)));
                Sr[lg * 4 + i][nc * 16 + lr] = f2bf(r * hD[nc][i]);
            }
        }
        #pragma unroll
        for (int nc = 0; nc < 8; ++nc){
            accZ[nc] = (f32x4){0.f, 0.f, 0.f, 0.f};
            #pragma unroll
            for (int kc = 0; kc < 4; ++kc){ s16x8 b = BF_LDS(kc, nc); MM1(accZ[nc], ah[kc], b); }
            if (nc & 1) __builtin_amdgcn_sched_barrier(0);
        }
        cur ^= 1;

        // ==== S4: [u_wxh ready] issue c_whh; accZ += x @ u_wxh (act deferred) ====
        __syncthreads();
        STAGE_MAT(4, cur ^ 1);
        #pragma unroll
        for (int nc = 0; nc < 8; ++nc){
            #pragma unroll
            for (int kc = 0; kc < 4; ++kc){ s16x8 b = BF_LDS(kc, nc); MM1(accZ[nc], xh[kc], b); }
            if ((nc & 3) == 3) __builtin_amdgcn_sched_barrier(0);
        }
        cur ^= 1;

        // ==== S5: [c_whh ready] issue c_wxh; DEFERRED z-act ∥ accC = (r*h)@c_whh ====
        __syncthreads();
        STAGE_MAT(5, cur ^ 1);
        // deferred Z-activation (z kept in accZ); interleaves with reads below
        #pragma unroll
        for (int nc = 0; nc < 8; ++nc){
            const float ubc = bias_s[1][nc * 16 + lr];
            #pragma unroll
            for (int i = 0; i < 4; ++i)
                accZ[nc][i] = 1.f / (1.f + __expf(-(accZ[nc][i] + ubc)));
        }
        #pragma unroll
        for (int kc = 0; kc < 4; ++kc)
            rhh[kc] = *(const s16x8*)&Sr[lr][kc * 32 + lg * 8];
        #pragma unroll
        for (int nc = 0; nc < 8; ++nc){
            accC[nc] = (f32x4){0.f, 0.f, 0.f, 0.f};
            #pragma unroll
            for (int kc = 0; kc < 4; ++kc){ s16x8 b = BF_LDS(kc, nc); MM1(accC[nc], rhh[kc], b); }
            if (nc & 1) __builtin_amdgcn_sched_barrier(0);
        }
        cur ^= 1;

        // ==== S6: [c_wxh ready] issue McT; accC += x @ c_wxh (act deferred) ====
        __syncthreads();
        STAGE_MAT(6, cur ^ 1);
        #pragma unroll
        for (int nc = 0; nc < 8; ++nc){
            #pragma unroll
            for (int kc = 0; kc < 4; ++kc){ s16x8 b = BF_LDS(kc, nc); MM1(accC[nc], xh[kc], b); }
            if ((nc & 3) == 3) __builtin_amdgcn_sched_barrier(0);
        }
        cur ^= 1;

        // ==== S7: [McT ready] issue next r_whh; DEFERRED C-act + h-update ∥ accO ====
        __syncthreads();
        if (t < Rr - 1) STAGE_MAT(0, cur ^ 1);
        // deferred C-activation + h-update; Sr = bf16(h'); interleaves with reads
        #pragma unroll
        for (int nc = 0; nc < 8; ++nc){
            const float cbc = bias_s[2][nc * 16 + lr];
            #pragma unroll
            for (int i = 0; i < 4; ++i){
                float e = __expf(2.f * (accC[nc][i] + cbc));
                float c = 1.f - 2.f / (e + 1.f);     // tanh, saturates correctly
                float ho = hD[nc][i];
                float hn = ho + accZ[nc][i] * (c - ho);
                hD[nc][i] = hn;
                Sr[lg * 4 + i][nc * 16 + lr] = f2bf(hn);
            }
        }
        #pragma unroll
        for (int kc = 0; kc < 4; ++kc)
            ah[kc] = *(const s16x8*)&Sr[lr][kc * 32 + lg * 8];
        #pragma unroll
        for (int nc = 0; nc < 8; ++nc){
            f32x4 ao = (f32x4){0.f, 0.f, 0.f, 0.f};
            #pragma unroll
            for (int kc = 0; kc < 4; ++kc){ s16x8 b = BF_LDS(kc, nc); MM1(ao, ah[kc], b); }
            const float obc = bias_s[3][nc * 16 + lr];
            #pragma unroll
            for (int i = 0; i < 4; ++i)
                Sr[lg * 4 + i][nc * 16 + lr] = f2bf(ao[i] + obc);
            if (nc & 1) __builtin_amdgcn_sched_barrier(0);
        }

        // epilogue: 32 lanes cover one 512-B out row; own-wave Sr (no barrier);
        // overlaps the in-flight next-t r_whh stage
        #pragma unroll
        for (int m = 0; m < 8; ++m){
            const int row = m * 2 + (l >> 5);
            const int c4  = (l & 31) * 4;
            const uint2 u = *(const uint2*)&Sr[row][c4];
            float4 v = { bf2f((unsigned short)(u.x & 0xffff)),
                         bf2f((unsigned short)(u.x >> 16)),
                         bf2f((unsigned short)(u.y & 0xffff)),
                         bf2f((unsigned short)(u.y >> 16)) };
            const int lo = loL[row], hi = hiL[row];
            for (int rr = lo; rr < hi; ++rr)
                *(float4*)(out + (size_t)rr * Hd + c4) = v;
        }
        cur ^= 1;
    }
    #undef STAGE_MAT
}

__global__ void he_order_kernel(const int* __restrict__ he_order,
                                float* __restrict__ out_tail, int nv)
{
    const int i = blockIdx.x * 256 + threadIdx.x;
    if (i < nv) out_tail[i] = (float)he_order[i];
}

extern "C" void kernel_launch(void* const* d_in, const int* in_sizes, int n_in,
                              void* d_out, int out_size, void* d_ws, size_t ws_size,
                              hipStream_t stream)
{
    const float* x_rank    = (const float*)d_in[0];
    // d_in[1] he_features, d_in[2] he_idx: dead (softmax over singleton axis == 1)
    const int*   valid_idx = (const int*)d_in[3];
    const int*   he_order  = (const int*)d_in[4];
    const float* r_whh = (const float*)d_in[5];
    const float* r_wxh = (const float*)d_in[6];
    const float* r_b   = (const float*)d_in[7];
    const float* u_whh = (const float*)d_in[8];
    const float* u_wxh = (const float*)d_in[9];
    const float* u_b   = (const float*)d_in[10];
    const float* c_whh = (const float*)d_in[11];
    const float* c_wxh = (const float*)d_in[12];
    const float* c_b   = (const float*)d_in[13];
    const float* in_proj_w = (const float*)d_in[14];
    const float* in_proj_b = (const float*)d_in[15];
    const float* out_w     = (const float*)d_in[16];
    const float* out_b     = (const float*)d_in[17];

    const int nv = in_sizes[3];
    const int N  = in_sizes[0] / (Rr * Hd);

    // workspace layout
    float* McT = (float*)d_ws;                         // 16384 f32
    float* bc  = McT + Hd * Hd;                        // 128 f32
    unsigned short* whi = (unsigned short*)(bc + Hd);  // 7*16384 u16

    float* out_f    = (float*)d_out;
    float* out_tail = out_f + (size_t)nv * Hd;

    fold_proj_kernel<<<Hd, Hd, 0, stream>>>(in_proj_w, in_proj_b, out_w, out_b, McT, bc);
    pack_kernel<<<dim3(32, 7), 64, 0, stream>>>(r_whh, u_whh, r_wxh, u_wxh, c_whh, c_wxh,
                                                McT, whi);

    const int nodes_per_block = NW * NPW;  // 128
    const int nblocks = (N + nodes_per_block - 1) / nodes_per_block;  // 235
    gru_mfma_kernel<<<nblocks, 512, 0, stream>>>(
        x_rank, valid_idx, nv, r_b, u_b, c_b, whi, bc, out_f, N);

    he_order_kernel<<<(nv + 255) / 256, 256, 0, stream>>>(he_order, out_tail, nv);
}

// Round 15
// 105.383 us; speedup vs baseline: 1.8305x; 1.0498x over previous
//
#include <hip/hip_runtime.h>
#include <math.h>

#define Hd 128
#define Rr 3
#define Ll 4
#define NPW 16   // nodes (M-rows) per wave
#define NW  8    // waves per block (512 threads)

typedef float f32x4 __attribute__((ext_vector_type(4)));
typedef short s16x8 __attribute__((ext_vector_type(8)));

__device__ __forceinline__ unsigned short f2bf(float f){
    unsigned u = __float_as_uint(f);
    return (unsigned short)((u + 0x7FFFu + ((u >> 16) & 1u)) >> 16);
}
__device__ __forceinline__ float bf2f(unsigned short h){
    return __uint_as_float(((unsigned)h) << 16);
}
__device__ __forceinline__ s16x8 cvt8(const float* p){
    float4 a = *(const float4*)p;
    float4 b = *(const float4*)(p + 4);
    float v[8] = {a.x, a.y, a.z, a.w, b.x, b.y, b.z, b.w};
    s16x8 r;
    #pragma unroll
    for (int j = 0; j < 8; ++j) r[j] = (short)f2bf(v[j]);
    return r;
}
__device__ __forceinline__ int lower_bound_i32(const int* __restrict__ a, int n, int key){
    int lo = 0, hi = n;
    while (lo < hi){
        int mid = (lo + hi) >> 1;
        if (a[mid] < key) lo = mid + 1; else hi = mid;
    }
    return lo;
}
__device__ __forceinline__ void gload_lds16(const unsigned short* g, unsigned short* l){
    __builtin_amdgcn_global_load_lds(
        (const __attribute__((address_space(1))) void*)g,
        (__attribute__((address_space(3))) void*)l, 16, 0, 0);
}
// unpack element i (0..3) of a D-layout bf16 pair-packed uint2
__device__ __forceinline__ float gxel(uint2 u, int i){
    unsigned w = (i < 2) ? u.x : u.y;
    return bf2f((unsigned short)((i & 1) ? (w >> 16) : (w & 0xffff)));
}

// ---- McT = out_w @ wv (folded), bc = out_w @ bv + out_b  (verified r1-r14) ----
__global__ void fold_proj_kernel(const float* __restrict__ in_proj_w,
                                 const float* __restrict__ in_proj_b,
                                 const float* __restrict__ out_w,
                                 const float* __restrict__ out_b,
                                 float* __restrict__ McT,
                                 float* __restrict__ bc)
{
    const int i = blockIdx.x;
    const int j = threadIdx.x;
    float acc = 0.f;
    for (int k = 0; k < Hd; ++k)
        acc = fmaf(out_w[j * Hd + k], in_proj_w[(2 * Hd + k) * Hd + i], acc);
    McT[i * Hd + j] = acc;
    if (i == 0){
        float b = out_b[j];
        for (int k = 0; k < Hd; ++k)
            b = fmaf(out_w[j * Hd + k], in_proj_b[2 * Hd + k], b);
        bc[j] = b;
    }
}

// ---- quantize weights to bf16 MFMA B-fragments (verified r4-r14) ----
// frag elem j of lane l at (mat,kc,nc):  W[kc*32 + (l>>4)*8 + j][nc*16 + (l&15)]
__global__ void pack_kernel(const float* __restrict__ r_whh, const float* __restrict__ u_whh,
                            const float* __restrict__ r_wxh, const float* __restrict__ u_wxh,
                            const float* __restrict__ c_whh, const float* __restrict__ c_wxh,
                            const float* __restrict__ McT,
                            unsigned short* __restrict__ whi)
{
    const int mat  = blockIdx.y;
    const int tile = blockIdx.x;
    const int l    = threadIdx.x;
    const float* W;
    switch (mat){
        case 0: W = r_whh; break;  case 1: W = u_whh; break;
        case 2: W = r_wxh; break;  case 3: W = u_wxh; break;
        case 4: W = c_whh; break;  case 5: W = c_wxh; break;
        default: W = McT;
    }
    const int kc = tile >> 3, nc = tile & 7;
    const int kbase = kc * 32 + (l >> 4) * 8;
    const int n = nc * 16 + (l & 15);
    const size_t obase = ((size_t)(mat * 32 + tile) * 64 + l) * 8;
    #pragma unroll
    for (int j = 0; j < 8; ++j)
        whi[obase + j] = f2bf(W[(kbase + j) * Hd + n]);
}

#define MM1(acc, AH, BH)                                                  \
    acc = __builtin_amdgcn_mfma_f32_16x16x32_bf16(AH, BH, acc, 0, 0, 0);

// ================= gx precompute: gx[g,t,node] = x@Wx_g + b_g (D-layout bf16) =================
__global__ __launch_bounds__(512, 1) void gx_kernel(
    const float* __restrict__ x_rank,
    const float* __restrict__ r_b, const float* __restrict__ u_b, const float* __restrict__ c_b,
    const unsigned short* __restrict__ whi,
    uint2* __restrict__ gx, int N, int NT)
{
    __shared__ __align__(16) unsigned short WX[3][16384];   // mats 2,3,5 (96 KB)
    const int tid = threadIdx.x;
    const int wid = tid >> 6;
    const int l   = tid & 63;
    const int lr  = l & 15;
    const int lg  = l >> 4;

    const int mats[3] = {2, 3, 5};
    #pragma unroll
    for (int m = 0; m < 3; ++m){
        const unsigned short* msrc = whi + (size_t)mats[m] * 16384;
        #pragma unroll
        for (int it = 0; it < 4; ++it){
            const int chunk = it * 8 + wid;
            gload_lds16(msrc + chunk * 512 + l * 8, &WX[m][chunk * 512]);
        }
    }
    __syncthreads();   // drains vmcnt: WX ready

    const int u = blockIdx.x * NW + wid;
    if (u >= 3 * NT) return;
    const int t  = u / NT;
    const int nt = u % NT;

    int nn = nt * NPW + lr; if (nn > N - 1) nn = N - 1;
    const float* xp = x_rank + ((size_t)nn * Rr + t) * Hd;
    s16x8 xh[4];
    #pragma unroll
    for (int kc = 0; kc < 4; ++kc)
        xh[kc] = cvt8(xp + kc * 32 + lg * 8);

    #pragma unroll
    for (int g = 0; g < 3; ++g){
        const float* bp = (g == 0) ? r_b : (g == 1) ? u_b : c_b;
        #pragma unroll
        for (int nc = 0; nc < 8; ++nc){
            f32x4 acc = (f32x4){0.f, 0.f, 0.f, 0.f};
            #pragma unroll
            for (int kc = 0; kc < 4; ++kc){
                s16x8 b = *(const s16x8*)&WX[g][(((kc) * 8 + nc) * 64 + l) * 8];
                MM1(acc, xh[kc], b);
            }
            const float bb = bp[nc * 16 + lr];
            uint2 o;
            o.x = ((unsigned)f2bf(acc[1] + bb) << 16) | f2bf(acc[0] + bb);
            o.y = ((unsigned)f2bf(acc[3] + bb) << 16) | f2bf(acc[2] + bb);
            gx[(((size_t)(g * Rr + t) * NT + nt) * 8 + nc) * 64 + l] = o;
            if ((nc & 3) == 3) __builtin_amdgcn_sched_barrier(0);
        }
    }
}

// ================= 9-phase recurrent kernel (h-matmuls + O only) =================
#define BF_LDS(kc, nc) (*(const s16x8*)&WL[cur][(((kc) * 8 + (nc)) * 64 + l) * 8])
#define GXLD(g, t, nc) gx[(((size_t)((g) * Rr + (t)) * NT + gtile) * 8 + (nc)) * 64 + l]

__global__ __launch_bounds__(512, 1) void gru_rec9_kernel(
    const int* __restrict__ valid_idx, int nv,
    const unsigned short* __restrict__ whi,
    const uint2* __restrict__ gx,
    const float* __restrict__ bc,
    float* __restrict__ out, int N, int NT)
{
    __shared__ __align__(16) unsigned short WL[2][16384];   // 64 KB double buffer
    __shared__ __align__(16) float Sr_all[NW][NPW][132];    // 67.6 KB
    __shared__ int lo_all[NW][NPW];
    __shared__ int hi_all[NW][NPW];

    const int tid = threadIdx.x;
    const int wid = tid >> 6;
    const int l   = tid & 63;
    const int lr  = l & 15;
    const int lg  = l >> 4;
    const int wtile = blockIdx.x * NW + wid;
    const int n0  = wtile * NPW;
    const int gtile = (wtile < NT) ? wtile : NT - 1;   // OOB waves: clamp (rows never stored)

    float (*Sr)[132] = Sr_all[wid];
    int* loL = lo_all[wid];
    int* hiL = hi_all[wid];

    #define STAGE_MAT(mat, b)                                                    \
        {                                                                        \
            const unsigned short* msrc = whi + (size_t)(mat) * 16384;            \
            _Pragma("unroll")                                                    \
            for (int it = 0; it < 4; ++it){                                      \
                const int chunk = it * 8 + wid;                                  \
                gload_lds16(msrc + chunk * 512 + l * 8, &WL[b][chunk * 512]);    \
            }                                                                    \
        }

    f32x4 hD[8];
    s16x8 ah[4], rhh[4];
    f32x4 zD[8];
    float obc[8];
    #pragma unroll
    for (int nc = 0; nc < 8; ++nc) obc[nc] = bc[nc * 16 + lr];

    unsigned cur = 0;
    STAGE_MAT(6, 0);          // prologue: McT into buf0

    #pragma unroll 1
    for (int t = 0; t < Rr; ++t){
        // ---- output-row ranges ----
        if (l < NPW){
            int n = n0 + l, lo = 0, hi = 0;
            if (n < N){
                int F = (n * Rr + t) * Ll;
                lo = lower_bound_i32(valid_idx, nv, F);
                hi = lower_bound_i32(valid_idx, nv, F + Ll);
            }
            loL[l] = lo; hiL[l] = hi;
        }

        if (t == 0){
            // h0 = 0: z = sig(gxu), c = tanh(gxc), h1 = z*c  (pure VALU, pre-barrier)
            uint2 gu[8], gc[8];
            #pragma unroll
            for (int nc = 0; nc < 8; ++nc){ gu[nc] = GXLD(1, 0, nc); gc[nc] = GXLD(2, 0, nc); }
            #pragma unroll
            for (int nc = 0; nc < 8; ++nc){
                #pragma unroll
                for (int i = 0; i < 4; ++i){
                    float z = 1.f / (1.f + __expf(-gxel(gu[nc], i)));
                    float e = __expf(2.f * gxel(gc[nc], i));
                    float c = 1.f - 2.f / (e + 1.f);
                    float hn = z * c;
                    hD[nc][i] = hn;
                    Sr[lg * 4 + i][nc * 16 + lr] = hn;
                }
            }
            #pragma unroll
            for (int kc = 0; kc < 4; ++kc)
                ah[kc] = cvt8(&Sr[lr][kc * 32 + lg * 8]);
        } else {
            // ==== S1: [r_whh ready] issue u_whh; accR = h@r_whh + gxr; Sr = r*h ====
            __syncthreads();
            STAGE_MAT(1, cur ^ 1);
            uint2 gr[8];
            #pragma unroll
            for (int nc = 0; nc < 8; ++nc) gr[nc] = GXLD(0, t, nc);
            #pragma unroll
            for (int nc = 0; nc < 8; ++nc){
                f32x4 accR = (f32x4){0.f, 0.f, 0.f, 0.f};
                #pragma unroll
                for (int kc = 0; kc < 4; ++kc){ s16x8 b = BF_LDS(kc, nc); MM1(accR, ah[kc], b); }
                #pragma unroll
                for (int i = 0; i < 4; ++i){
                    float r = 1.f / (1.f + __expf(-(accR[i] + gxel(gr[nc], i))));
                    Sr[lg * 4 + i][nc * 16 + lr] = r * hD[nc][i];
                }
                if ((nc & 3) == 3) __builtin_amdgcn_sched_barrier(0);
            }
            cur ^= 1;

            // ==== S2: [u_whh ready] issue c_whh; z = sig(h@u_whh + gxu); rh frags ====
            __syncthreads();
            STAGE_MAT(4, cur ^ 1);
            uint2 gu[8];
            #pragma unroll
            for (int nc = 0; nc < 8; ++nc) gu[nc] = GXLD(1, t, nc);
            #pragma unroll
            for (int nc = 0; nc < 8; ++nc){
                f32x4 accZ = (f32x4){0.f, 0.f, 0.f, 0.f};
                #pragma unroll
                for (int kc = 0; kc < 4; ++kc){ s16x8 b = BF_LDS(kc, nc); MM1(accZ, ah[kc], b); }
                #pragma unroll
                for (int i = 0; i < 4; ++i)
                    zD[nc][i] = 1.f / (1.f + __expf(-(accZ[i] + gxel(gu[nc], i))));
                if ((nc & 3) == 3) __builtin_amdgcn_sched_barrier(0);
            }
            #pragma unroll
            for (int kc = 0; kc < 4; ++kc)
                rhh[kc] = cvt8(&Sr[lr][kc * 32 + lg * 8]);
            cur ^= 1;

            // ==== S3: [c_whh ready] issue McT; c = tanh(rh@c_whh + gxc); h update ====
            __syncthreads();
            STAGE_MAT(6, cur ^ 1);
            uint2 gc[8];
            #pragma unroll
            for (int nc = 0; nc < 8; ++nc) gc[nc] = GXLD(2, t, nc);
            #pragma unroll
            for (int nc = 0; nc < 8; ++nc){
                f32x4 accC = (f32x4){0.f, 0.f, 0.f, 0.f};
                #pragma unroll
                for (int kc = 0; kc < 4; ++kc){ s16x8 b = BF_LDS(kc, nc); MM1(accC, rhh[kc], b); }
                #pragma unroll
                for (int i = 0; i < 4; ++i){
                    float e = __expf(2.f * (accC[i] + gxel(gc[nc], i)));
                    float c = 1.f - 2.f / (e + 1.f);
                    float ho = hD[nc][i];
                    float hn = ho + zD[nc][i] * (c - ho);
                    hD[nc][i] = hn;
                    Sr[lg * 4 + i][nc * 16 + lr] = hn;
                }
                if ((nc & 3) == 3) __builtin_amdgcn_sched_barrier(0);
            }
            #pragma unroll
            for (int kc = 0; kc < 4; ++kc)
                ah[kc] = cvt8(&Sr[lr][kc * 32 + lg * 8]);
            cur ^= 1;
        }

        // ==== O: [McT ready] issue next-t r_whh; accO = h'@McT + bc; scatter ====
        __syncthreads();
        if (t < Rr - 1) STAGE_MAT(0, cur ^ 1);
        #pragma unroll
        for (int nc = 0; nc < 8; ++nc){
            f32x4 ao = (f32x4){0.f, 0.f, 0.f, 0.f};
            #pragma unroll
            for (int kc = 0; kc < 4; ++kc){ s16x8 b = BF_LDS(kc, nc); MM1(ao, ah[kc], b); }
            #pragma unroll
            for (int i = 0; i < 4; ++i)
                Sr[lg * 4 + i][nc * 16 + lr] = ao[i] + obc[nc];
            if ((nc & 3) == 3) __builtin_amdgcn_sched_barrier(0);
        }
        // epilogue: 32 lanes cover one 512-B out row; own-wave Sr (in-order)
        #pragma unroll
        for (int m = 0; m < 8; ++m){
            const int row = m * 2 + (l >> 5);
            const int c4  = (l & 31) * 4;
            const float4 v = *(const float4*)&Sr[row][c4];
            const int lo = loL[row], hi = hiL[row];
            for (int rr = lo; rr < hi; ++rr)
                *(float4*)(out + (size_t)rr * Hd + c4) = v;
        }
        cur ^= 1;
    }
    #undef STAGE_MAT
}

// ================= fallback: round-9 kernel (used if ws_size too small) =================
__global__ __launch_bounds__(512, 1) void gru_mfma_fb(
    const float* __restrict__ x_rank,
    const int* __restrict__ valid_idx, int nv,
    const float* __restrict__ r_b, const float* __restrict__ u_b, const float* __restrict__ c_b,
    const unsigned short* __restrict__ whi,
    const float* __restrict__ bc,
    float* __restrict__ out, int N)
{
    __shared__ __align__(16) unsigned short WL[2][16384];
    __shared__ __align__(16) float Sr_all[NW][NPW][132];
    __shared__ float bias_s[4][Hd];
    __shared__ int lo_all[NW][NPW];
    __shared__ int hi_all[NW][NPW];

    const int tid = threadIdx.x;
    const int wid = tid >> 6;
    const int l   = tid & 63;
    const int lr  = l & 15;
    const int lg  = l >> 4;
    const int n0  = (blockIdx.x * NW + wid) * NPW;

    float (*Sr)[132] = Sr_all[wid];
    int* loL = lo_all[wid];
    int* hiL = hi_all[wid];

    if (tid < Hd){
        bias_s[0][tid] = r_b[tid];
        bias_s[1][tid] = u_b[tid];
        bias_s[2][tid] = c_b[tid];
        bias_s[3][tid] = bc[tid];
    }
    #define STAGE_MAT(mat, b)                                                    \
        {                                                                        \
            const unsigned short* msrc = whi + (size_t)(mat) * 16384;            \
            _Pragma("unroll")                                                    \
            for (int it = 0; it < 4; ++it){                                      \
                const int chunk = it * 8 + wid;                                  \
                gload_lds16(msrc + chunk * 512 + l * 8, &WL[b][chunk * 512]);    \
            }                                                                    \
        }
    f32x4 hD[8];
    s16x8 ah[4];
    #pragma unroll
    for (int nc = 0; nc < 8; ++nc) hD[nc] = (f32x4){0.f, 0.f, 0.f, 0.f};
    #pragma unroll
    for (int kc = 0; kc < 4; ++kc) ah[kc] = (s16x8)0;
    s16x8 xh[4], rhh[4];

    unsigned cur = 0;
    STAGE_MAT(0, 0);

    #pragma unroll 1
    for (int t = 0; t < Rr; ++t){
        if (l < NPW){
            int n = n0 + l, lo = 0, hi = 0;
            if (n < N){
                int F = (n * Rr + t) * Ll;
                lo = lower_bound_i32(valid_idx, nv, F);
                hi = lower_bound_i32(valid_idx, nv, F + Ll);
            }
            loL[l] = lo; hiL[l] = hi;
        }
        {
            int nn = n0 + lr; if (nn > N - 1) nn = N - 1;
            const float* xp = x_rank + ((size_t)nn * Rr + t) * Hd;
            #pragma unroll
            for (int kc = 0; kc < 4; ++kc)
                xh[kc] = cvt8(xp + kc * 32 + lg * 8);
        }
        f32x4 accR[8], accZ[8];
        __syncthreads();
        STAGE_MAT(2, cur ^ 1);
        #pragma unroll
        for (int nc = 0; nc < 8; ++nc){
            accR[nc] = (f32x4){0.f, 0.f, 0.f, 0.f};
            #pragma unroll
            for (int kc = 0; kc < 4; ++kc){ s16x8 b = BF_LDS(kc, nc); MM1(accR[nc], ah[kc], b); }
            if ((nc & 3) == 3) __builtin_amdgcn_sched_barrier(0);
        }
        cur ^= 1;
        __syncthreads();
        STAGE_MAT(1, cur ^ 1);
        #pragma unroll
        for (int nc = 0; nc < 8; ++nc){
            #pragma unroll
            for (int kc = 0; kc < 4; ++kc){ s16x8 b = BF_LDS(kc, nc); MM1(accR[nc], xh[kc], b); }
            const float rbc = bias_s[0][nc * 16 + lr];
            #pragma unroll
            for (int i = 0; i < 4; ++i){
                float r = 1.f / (1.f + __expf(-(accR[nc][i] + rbc)));
                Sr[lg * 4 + i][nc * 16 + lr] = r * hD[nc][i];
            }
            if ((nc & 3) == 3) __builtin_amdgcn_sched_barrier(0);
        }
        cur ^= 1;
        __syncthreads();
        STAGE_MAT(3, cur ^ 1);
        #pragma unroll
        for (int nc = 0; nc < 8; ++nc){
            accZ[nc] = (f32x4){0.f, 0.f, 0.f, 0.f};
            #pragma unroll
            for (int kc = 0; kc < 4; ++kc){ s16x8 b = BF_LDS(kc, nc); MM1(accZ[nc], ah[kc], b); }
            if ((nc & 3) == 3) __builtin_amdgcn_sched_barrier(0);
        }
        cur ^= 1;
        __syncthreads();
        STAGE_MAT(4, cur ^ 1);
        #pragma unroll
        for (int nc = 0; nc < 8; ++nc){
            #pragma unroll
            for (int kc = 0; kc < 4; ++kc){ s16x8 b = BF_LDS(kc, nc); MM1(accZ[nc], xh[kc], b); }
            const float ubc = bias_s[1][nc * 16 + lr];
            #pragma unroll
            for (int i = 0; i < 4; ++i)
                accZ[nc][i] = 1.f / (1.f + __expf(-(accZ[nc][i] + ubc)));
            if ((nc & 3) == 3) __builtin_amdgcn_sched_barrier(0);
        }
        cur ^= 1;
        __syncthreads();
        STAGE_MAT(5, cur ^ 1);
        #pragma unroll
        for (int kc = 0; kc < 4; ++kc)
            rhh[kc] = cvt8(&Sr[lr][kc * 32 + lg * 8]);
        f32x4 accC[8];
        #pragma unroll
        for (int nc = 0; nc < 8; ++nc){
            accC[nc] = (f32x4){0.f, 0.f, 0.f, 0.f};
            #pragma unroll
            for (int kc = 0; kc < 4; ++kc){ s16x8 b = BF_LDS(kc, nc); MM1(accC[nc], rhh[kc], b); }
            if ((nc & 3) == 3) __builtin_amdgcn_sched_barrier(0);
        }
        cur ^= 1;
        __syncthreads();
        STAGE_MAT(6, cur ^ 1);
        #pragma unroll
        for (int nc = 0; nc < 8; ++nc){
            #pragma unroll
            for (int kc = 0; kc < 4; ++kc){ s16x8 b = BF_LDS(kc, nc); MM1(accC[nc], xh[kc], b); }
            const float cbc = bias_s[2][nc * 16 + lr];
            #pragma unroll
            for (int i = 0; i < 4; ++i){
                float e = __expf(2.f * (accC[nc][i] + cbc));
                float c = 1.f - 2.f / (e + 1.f);
                float ho = hD[nc][i];
                float hn = ho + accZ[nc][i] * (c - ho);
                hD[nc][i] = hn;
                Sr[lg * 4 + i][nc * 16 + lr] = hn;
            }
            if ((nc & 3) == 3) __builtin_amdgcn_sched_barrier(0);
        }
        #pragma unroll
        for (int kc = 0; kc < 4; ++kc)
            ah[kc] = cvt8(&Sr[lr][kc * 32 + lg * 8]);
        cur ^= 1;
        __syncthreads();
        if (t < Rr - 1) STAGE_MAT(0, cur ^ 1);
        #pragma unroll
        for (int nc = 0; nc < 8; ++nc){
            f32x4 ao = (f32x4){0.f, 0.f, 0.f, 0.f};
            #pragma unroll
            for (int kc = 0; kc < 4; ++kc){ s16x8 b = BF_LDS(kc, nc); MM1(ao, ah[kc], b); }
            const float obc = bias_s[3][nc * 16 + lr];
            #pragma unroll
            for (int i = 0; i < 4; ++i)
                Sr[lg * 4 + i][nc * 16 + lr] = ao[i] + obc;
            if ((nc & 3) == 3) __builtin_amdgcn_sched_barrier(0);
        }
        #pragma unroll
        for (int m = 0; m < 8; ++m){
            const int row = m * 2 + (l >> 5);
            const int c4  = (l & 31) * 4;
            const float4 v = *(const float4*)&Sr[row][c4];
            const int lo = loL[row], hi = hiL[row];
            for (int rr = lo; rr < hi; ++rr)
                *(float4*)(out + (size_t)rr * Hd + c4) = v;
        }
        cur ^= 1;
    }
    #undef STAGE_MAT
}

__global__ void he_order_kernel(const int* __restrict__ he_order,
                                float* __restrict__ out_tail, int nv)
{
    const int i = blockIdx.x * 256 + threadIdx.x;
    if (i < nv) out_tail[i] = (float)he_order[i];
}

extern "C" void kernel_launch(void* const* d_in, const int* in_sizes, int n_in,
                              void* d_out, int out_size, void* d_ws, size_t ws_size,
                              hipStream_t stream)
{
    const float* x_rank    = (const float*)d_in[0];
    // d_in[1] he_features, d_in[2] he_idx: dead (softmax over singleton axis == 1)
    const int*   valid_idx = (const int*)d_in[3];
    const int*   he_order  = (const int*)d_in[4];
    const float* r_whh = (const float*)d_in[5];
    const float* r_wxh = (const float*)d_in[6];
    const float* r_b   = (const float*)d_in[7];
    const float* u_whh = (const float*)d_in[8];
    const float* u_wxh = (const float*)d_in[9];
    const float* u_b   = (const float*)d_in[10];
    const float* c_whh = (const float*)d_in[11];
    const float* c_wxh = (const float*)d_in[12];
    const float* c_b   = (const float*)d_in[13];
    const float* in_proj_w = (const float*)d_in[14];
    const float* in_proj_b = (const float*)d_in[15];
    const float* out_w     = (const float*)d_in[16];
    const float* out_b     = (const float*)d_in[17];

    const int nv = in_sizes[3];
    const int N  = in_sizes[0] / (Rr * Hd);
    const int NT = (N + NPW - 1) / NPW;   // 1875

    // workspace layout
    float* McT = (float*)d_ws;                           // 16384 f32
    float* bc  = McT + Hd * Hd;                          // 128 f32
    unsigned short* whi = (unsigned short*)(bc + Hd);    // 7*16384 u16
    const size_t base = 16384*4 + 128*4 + 7*16384*2;     // 295424 B
    uint2* gx = (uint2*)((char*)d_ws + base);
    const size_t gx_bytes = (size_t)9 * NT * 8 * 64 * 8; // 69.12 MB

    float* out_f    = (float*)d_out;
    float* out_tail = out_f + (size_t)nv * Hd;

    fold_proj_kernel<<<Hd, Hd, 0, stream>>>(in_proj_w, in_proj_b, out_w, out_b, McT, bc);
    pack_kernel<<<dim3(32, 7), 64, 0, stream>>>(r_whh, u_whh, r_wxh, u_wxh, c_whh, c_wxh,
                                                McT, whi);

    const int nodes_per_block = NW * NPW;  // 128
    const int nblocks = (N + nodes_per_block - 1) / nodes_per_block;  // 235

    if (ws_size >= base + gx_bytes){
        const int gxblocks = (3 * NT + NW - 1) / NW;   // 704
        gx_kernel<<<gxblocks, 512, 0, stream>>>(x_rank, r_b, u_b, c_b, whi, gx, N, NT);
        gru_rec9_kernel<<<nblocks, 512, 0, stream>>>(valid_idx, nv, whi, gx, bc, out_f, N, NT);
    } else {
        gru_mfma_fb<<<nblocks, 512, 0, stream>>>(
            x_rank, valid_idx, nv, r_b, u_b, c_b, whi, bc, out_f, N);
    }

    he_order_kernel<<<(nv + 255) / 256, 256, 0, stream>>>(he_order, out_tail, nv);
}